// Round 15
// baseline (70.180 us; speedup 1.0000x reference)
//
#include <hip/hip_runtime.h>
#include <hip/hip_bf16.h>

// Problem constants
#define BB 64
#define CC 512
#define DD 256
// loss = mean_{b,c} [ log(sum_k exp(2*S_bck)) - 2*S_bcc ],  S = Vn . Tn^T (rows L2-normalized)

typedef __attribute__((ext_vector_type(8))) short bf16x8;  // 8 bf16 = 4 VGPRs
typedef __attribute__((ext_vector_type(4))) float f32x4;
typedef unsigned int u32;

#define SWZ(r) (((r) & 7) << 4)
#define TWO_LOG2E 2.8853900817779268f  // 2*log2(e): A pre-scale so acc = 2*log2e*S
#define LN2 0.6931471805599453f        // acc*ln2 = 2*S

__device__ inline short f2bf(float f) {
    union { __hip_bfloat16 h; short s; } cv;
    cv.h = __float2bfloat16(f);
    return cv.s;
}

// ---------------- Pass 1: L2-normalize T rows (fp32 in -> bf16 out), ~85% HBM ----------------
__global__ __launch_bounds__(256) void norm_rows(const float* __restrict__ in,
                                                 unsigned short* __restrict__ out) {
    const int row  = blockIdx.x * 4 + (threadIdx.x >> 6);
    const int lane = threadIdx.x & 63;
    const float4 x = reinterpret_cast<const float4*>(in)[(size_t)row * 64 + lane];
    float ss = x.x * x.x + x.y * x.y + x.z * x.z + x.w * x.w;
#pragma unroll
    for (int off = 32; off; off >>= 1) ss += __shfl_xor(ss, off);
    const float r = 1.0f / fmaxf(sqrtf(ss), 1e-12f);
    ushort4 o;
    o.x = (unsigned short)f2bf(x.x * r);
    o.y = (unsigned short)f2bf(x.y * r);
    o.z = (unsigned short)f2bf(x.z * r);
    o.w = (unsigned short)f2bf(x.w * r);
    reinterpret_cast<ushort4*>(out)[(size_t)row * 64 + lane] = o;
}

// ---------------- Pass 2: fused V-norm + GEMM + loss + LAST-BLOCK FINAL REDUCE ----------
// R11 structure (35.5 us total, confirmed R14): 256 blocks = 64 batches x 4 row-blocks of
// 128 V-rows; 512 threads (8 waves: wr=wave>>1 owns a 32-row band, wc=wave&1 owns 32 of
// each 64-col tile). 8 tile-phases (64 T-rows, 32 KB), FOUR buffers, DMA depth 3
// (counted s_waitcnt vmcnt(8), never drained mid-loop), ONE barrier per tile.
// New vs R14: (1) A pre-scaled by 2*log2(e) so the epilogue is a bare v_exp_f32;
// (2) no third kernel: blocks release-store partials, fetch_add a counter (memset to 0
// each call), and the LAST block acquire-loads all 256 partials and writes d_out.
__global__ __launch_bounds__(512, 1) void gemm_loss(const float* __restrict__ V,
                                                    const unsigned short* __restrict__ Tn,
                                                    float* __restrict__ partials,
                                                    unsigned* __restrict__ counter,
                                                    float* __restrict__ out) {
    extern __shared__ char lds[];  // 4 x 32KB tile buffers (prologue: A staging in [0,64K))
    float* vred = reinterpret_cast<float*>(lds + 131072);  // [128 rows][2 wc]
    float* dred = vred + 256;                              // [128 rows][2 wc]
    float* red2 = dred + 256;                              // [2]
    __shared__ unsigned lastflag;
    __shared__ float fr[8];

    // XCD-aware remap: the 4 rb-blocks of one batch land on one XCD (Tn panel L2 reuse)
    const int i0    = blockIdx.x;  // 0..255
    const int inner = i0 & 63;
    const int b     = (inner & 7) * 8 + (inner >> 3);  // bijective over 0..63
    const int rb    = i0 >> 6;                         // 0..3

    const int tid  = threadIdx.x;  // 0..511
    const int lane = tid & 63;
    const int wave = tid >> 6;     // 0..7
    const int wr   = wave >> 1;    // 32-row band of the 128 block rows
    const int wc   = wave & 1;     // 32-col half of each 64-col tile
    const int g    = lane >> 4;    // k-group 0..3
    const int ln   = lane & 15;

    const float* gV = V + (size_t)b * (CC * DD) + (size_t)rb * 128 * DD;
    const char*  gT = reinterpret_cast<const char*>(Tn + (size_t)b * (CC * DD));  // 512 B rows

    // ---- A prologue: load 128 fp32 V rows, L2-normalize (x 2*log2e), bf16 swizzled to lds ----
    {
        const int rrow  = tid >> 3;        // 8 threads/row, 64 rows/pass
        const int ecolB = (tid & 7) * 64;  // byte offset of this thread's 32 bf16 elems
#pragma unroll
        for (int p = 0; p < 2; ++p) {
            const int row = p * 64 + rrow;
            const float4* src =
                reinterpret_cast<const float4*>(gV + (size_t)row * DD) + (tid & 7) * 8;
            float4 x[8];
#pragma unroll
            for (int q = 0; q < 8; ++q) x[q] = src[q];
            float ss = 0.f;
#pragma unroll
            for (int q = 0; q < 8; ++q)
                ss += x[q].x * x[q].x + x[q].y * x[q].y + x[q].z * x[q].z + x[q].w * x[q].w;
            ss += __shfl_xor(ss, 1);
            ss += __shfl_xor(ss, 2);
            ss += __shfl_xor(ss, 4);  // 8 lanes own the row
            const float rinv = TWO_LOG2E / fmaxf(sqrtf(ss), 1e-12f);
            char* dstrow = lds + row * 512;
            const int sw = SWZ(row);
#pragma unroll
            for (int q2 = 0; q2 < 4; ++q2) {
                const float4 v0 = x[2 * q2], v1 = x[2 * q2 + 1];
                bf16x8 o;
                o[0] = f2bf(v0.x * rinv); o[1] = f2bf(v0.y * rinv);
                o[2] = f2bf(v0.z * rinv); o[3] = f2bf(v0.w * rinv);
                o[4] = f2bf(v1.x * rinv); o[5] = f2bf(v1.y * rinv);
                o[6] = f2bf(v1.z * rinv); o[7] = f2bf(v1.w * rinv);
                *reinterpret_cast<bf16x8*>(dstrow + ((ecolB + q2 * 16) ^ sw)) = o;
            }
        }
    }
    __syncthreads();

    // ---- cache this wave's A fragments: rows [wr*32, +32) -> a[2][8] = 64 VGPR ----
    bf16x8 a[2][8];
#pragma unroll
    for (int i = 0; i < 2; ++i) {
        const int row  = wr * 32 + i * 16 + ln;
        const char* rp = lds + row * 512;
        const int sw   = SWZ(row);
#pragma unroll
        for (int kk = 0; kk < 8; ++kk)
            a[i][kk] = *reinterpret_cast<const bf16x8*>(rp + ((kk * 64 + g * 16) ^ sw));
    }
    __syncthreads();  // implicit vmcnt(0): clean counter; lds free for tile buffers

    // ---- DMA stage: tile t = 64 Tn rows (32 KB) -> buf[t%4]; wave stages rows [wave*8,+8) ----
    auto stage = [&](int t) {
        const char* gtile = gT + (size_t)t * 32768;
        char* dst = lds + (t & 3) * 32768 + wave * 4096;
#pragma unroll
        for (int r2 = 0; r2 < 4; ++r2) {
            const int L   = r2 * 1024 + (lane << 4);
            const int lr  = L >> 9;  // 0..7 local row (within wave's 8)
            const int row = wave * 8 + lr;
            const int inrow = L & 511;
            __builtin_amdgcn_global_load_lds(
                (const u32*)(gtile + (size_t)row * 512 + (inrow ^ SWZ(row))),
                (u32*)(dst + r2 * 1024), 16, 0, 0);
        }
    };
    stage(0);
    stage(1);
    stage(2);  // 12 loads in flight per wave (depth 3)

    float rs[2][4];  // rowsum of exp(2S) over this wave's cols, per (i, r)
    float dg[2][4];  // diagonal 2*S term
#pragma unroll
    for (int i = 0; i < 2; ++i)
#pragma unroll
        for (int r = 0; r < 4; ++r) { rs[i][r] = 0.f; dg[i][r] = 0.f; }

    for (int t = 0; t < 8; ++t) {  // NOT unrolled (register pressure)
        // counted wait: my 4 tile-t loads landed (t+1,t+2's 8 stay in flight); then all waves'
        if (t < 6)       asm volatile("s_waitcnt vmcnt(8)" ::: "memory");
        else if (t == 6) asm volatile("s_waitcnt vmcnt(4)" ::: "memory");
        else             asm volatile("s_waitcnt vmcnt(0)" ::: "memory");
        __builtin_amdgcn_s_barrier();
        __builtin_amdgcn_sched_barrier(0);
        // stage t+3 into buf[(t+3)%4] = buf[(t-1)%4]; the barrier above proved every wave
        // finished consuming tile t-1 -> WAR-safe with ONE barrier per tile
        if (t < 5) stage(t + 3);

        // ---- consume tile t: 16 ds_read + 32 MFMA (acc 2x2 fragments = 32x32 output) ----
        const char* bufp = lds + (t & 3) * 32768;
        const int row0 = wc * 32 + ln;        // jc=0 B-row
        const int row1 = wc * 32 + 16 + ln;   // jc=1 B-row
        const char* rp0 = bufp + row0 * 512;
        const char* rp1 = bufp + row1 * 512;
        const int sw0 = SWZ(row0), sw1 = SWZ(row1);
        f32x4 acc[2][2];
#pragma unroll
        for (int i = 0; i < 2; ++i)
#pragma unroll
            for (int j = 0; j < 2; ++j) acc[i][j] = (f32x4){0.f, 0.f, 0.f, 0.f};
        __builtin_amdgcn_s_setprio(1);
#pragma unroll
        for (int kk = 0; kk < 8; ++kk) {
            const int ko = kk * 64 + g * 16;
            const bf16x8 b0 = *reinterpret_cast<const bf16x8*>(rp0 + (ko ^ sw0));
            const bf16x8 b1 = *reinterpret_cast<const bf16x8*>(rp1 + (ko ^ sw1));
            acc[0][0] = __builtin_amdgcn_mfma_f32_16x16x32_bf16(a[0][kk], b0, acc[0][0], 0, 0, 0);
            acc[1][0] = __builtin_amdgcn_mfma_f32_16x16x32_bf16(a[1][kk], b0, acc[1][0], 0, 0, 0);
            acc[0][1] = __builtin_amdgcn_mfma_f32_16x16x32_bf16(a[0][kk], b1, acc[0][1], 0, 0, 0);
            acc[1][1] = __builtin_amdgcn_mfma_f32_16x16x32_bf16(a[1][kk], b1, acc[1][1], 0, 0, 0);
        }
        __builtin_amdgcn_s_setprio(0);

        // ---- fused epilogue: acc = 2*log2e*S, so exp(2S) = exp2(acc), 2S = acc*ln2 ----
        if ((t >> 1) == rb) {
#pragma unroll
            for (int i = 0; i < 2; ++i) {
                const int grow = rb * 128 + wr * 32 + i * 16 + g * 4;  // + r
#pragma unroll
                for (int j = 0; j < 2; ++j) {
                    const int gcol = t * 64 + wc * 32 + j * 16 + ln;
#pragma unroll
                    for (int r = 0; r < 4; ++r) {
                        const float av = acc[i][j][r];
                        rs[i][r] += __builtin_amdgcn_exp2f(av);
                        if (gcol == grow + r) dg[i][r] += av * LN2;
                    }
                }
            }
        } else {
#pragma unroll
            for (int i = 0; i < 2; ++i)
#pragma unroll
                for (int j = 0; j < 2; ++j)
#pragma unroll
                    for (int r = 0; r < 4; ++r)
                        rs[i][r] += __builtin_amdgcn_exp2f(acc[i][j][r]);
        }
    }

    // ---- per-row completion: combine the two wc-halves' exp-sums BEFORE log ----
#pragma unroll
    for (int i = 0; i < 2; ++i)
#pragma unroll
        for (int r = 0; r < 4; ++r) {
            float v = rs[i][r];
            float d = dg[i][r];
#pragma unroll
            for (int m = 1; m < 16; m <<= 1) {  // reduce the 16 column-lanes
                v += __shfl_xor(v, m);
                d += __shfl_xor(d, m);
            }
            if (ln == 0) {
                const int rl = wr * 32 + i * 16 + g * 4 + r;  // local row 0..127
                vred[rl * 2 + wc] = v;
                dred[rl * 2 + wc] = d;
            }
        }
    __syncthreads();

    if (tid < 128) {
        const float vv = vred[tid * 2] + vred[tid * 2 + 1];
        const float dd = dred[tid * 2] + dred[tid * 2 + 1];
        float lsum = logf(vv) - dd;
#pragma unroll
        for (int m = 1; m < 64; m <<= 1) lsum += __shfl_xor(lsum, m);
        if (lane == 0) red2[wave] = lsum;  // waves 0,1
    }
    __syncthreads();

    // ---- publish partial; last block to finish does the final reduce into d_out ----
    if (tid == 0) {
        __hip_atomic_store(&partials[i0], red2[0] + red2[1], __ATOMIC_RELEASE,
                           __HIP_MEMORY_SCOPE_AGENT);
        const unsigned prev =
            __hip_atomic_fetch_add(counter, 1u, __ATOMIC_ACQ_REL, __HIP_MEMORY_SCOPE_AGENT);
        lastflag = (prev == 255u) ? 1u : 0u;
    }
    __syncthreads();
    if (lastflag) {
        float v = 0.f;
        if (tid < 256)
            v = __hip_atomic_load(&partials[tid], __ATOMIC_ACQUIRE, __HIP_MEMORY_SCOPE_AGENT);
#pragma unroll
        for (int m = 1; m < 64; m <<= 1) v += __shfl_xor(v, m);  // fixed order: deterministic
        if (lane == 0) fr[wave] = v;
        __syncthreads();
        if (tid == 0) {
            float s = 0.f;
#pragma unroll
            for (int w = 0; w < 8; ++w) s += fr[w];
            out[0] = s * (1.0f / 32768.0f);
        }
    }
}

extern "C" void kernel_launch(void* const* d_in, const int* in_sizes, int n_in,
                              void* d_out, int out_size, void* d_ws, size_t ws_size,
                              hipStream_t stream) {
    const float* vis = (const float*)d_in[0];
    const float* txt = (const float*)d_in[1];

    unsigned short* Tn = (unsigned short*)d_ws;                             // 16.8 MB
    float* partials    = (float*)((char*)d_ws + (size_t)BB * CC * DD * 2);  // 256 floats
    unsigned* counter  = (unsigned*)(partials + 256);                       // 1 u32
    float* out         = (float*)d_out;

    const int lds_bytes = 131072 + 256 * 4 + 256 * 4 + 16;
    hipFuncSetAttribute((const void*)gemm_loss, hipFuncAttributeMaxDynamicSharedMemorySize,
                        lds_bytes);

    hipMemsetAsync(counter, 0, sizeof(unsigned), stream);  // reset last-block counter
    norm_rows<<<8192, 256, 0, stream>>>(txt, Tn);
    gemm_loss<<<256, 512, lds_bytes, stream>>>(vis, Tn, partials, counter, out);
}

// Round 16
// 35.645 us; speedup vs baseline: 1.9688x; 1.9688x over previous
//
#include <hip/hip_runtime.h>
#include <hip/hip_bf16.h>

// Problem constants
#define BB 64
#define CC 512
#define DD 256
// loss = mean_{b,c} [ log(sum_k exp(2*S_bck)) - 2*S_bcc ],  S = Vn . Tn^T (rows L2-normalized)

typedef __attribute__((ext_vector_type(8))) short bf16x8;  // 8 bf16 = 4 VGPRs
typedef __attribute__((ext_vector_type(4))) float f32x4;
typedef unsigned int u32;

#define SWZ(r) (((r) & 7) << 4)

__device__ inline short f2bf(float f) {
    union { __hip_bfloat16 h; short s; } cv;
    cv.h = __float2bfloat16(f);
    return cv.s;
}

// ---------------- Pass 1: L2-normalize T rows (fp32 in -> bf16 out), ~85% HBM ----------------
__global__ __launch_bounds__(256) void norm_rows(const float* __restrict__ in,
                                                 unsigned short* __restrict__ out) {
    const int row  = blockIdx.x * 4 + (threadIdx.x >> 6);
    const int lane = threadIdx.x & 63;
    const float4 x = reinterpret_cast<const float4*>(in)[(size_t)row * 64 + lane];
    float ss = x.x * x.x + x.y * x.y + x.z * x.z + x.w * x.w;
#pragma unroll
    for (int off = 32; off; off >>= 1) ss += __shfl_xor(ss, off);
    const float r = 1.0f / fmaxf(sqrtf(ss), 1e-12f);
    ushort4 o;
    o.x = (unsigned short)f2bf(x.x * r);
    o.y = (unsigned short)f2bf(x.y * r);
    o.z = (unsigned short)f2bf(x.z * r);
    o.w = (unsigned short)f2bf(x.w * r);
    reinterpret_cast<ushort4*>(out)[(size_t)row * 64 + lane] = o;
}

// ---------------- Pass 2: fused V-norm + GEMM + loss (R11 optimum — terminal config) --------
// 256 blocks = 64 batches x 4 row-blocks of 128 V-rows; 512 threads (8 waves: wr=wave>>1
// owns a 32-row band, wc=wave&1 owns 32 of each 64-col tile). 8 tile-phases (64 T-rows,
// 32 KB each), FOUR LDS buffers, prefetch depth 3 (12 gload_lds in flight, counted
// s_waitcnt vmcnt(8), never drained mid-loop). One barrier per tile: stage(t+3) lands in
// buf[(t+3)%4]=buf[(t-1)%4], and barrier t proves all waves consumed t-1 (WAR-safe).
// Per tile per wave: 16 ds_read_b128 + 32 MFMA + 16 exp. A: 128 fp32 V rows normalized
// in prologue (read once from HBM), cached in regs a[2][8].
// NOTE (R15 lesson, rule #19): do NOT fold the final reduce into this kernel — the added
// tail perturbs regalloc (VGPR 120->84) and serializes the ds_read/MFMA pipeline (-24 us).
__global__ __launch_bounds__(512, 1) void gemm_loss(const float* __restrict__ V,
                                                    const unsigned short* __restrict__ Tn,
                                                    float* __restrict__ partials) {
    extern __shared__ char lds[];  // 4 x 32KB tile buffers (prologue: A staging in [0,64K))
    float* vred = reinterpret_cast<float*>(lds + 131072);  // [128 rows][2 wc]
    float* dred = vred + 256;                              // [128 rows][2 wc]
    float* red2 = dred + 256;                              // [2]

    // XCD-aware remap: the 4 rb-blocks of one batch land on one XCD (Tn panel L2 reuse)
    const int i0    = blockIdx.x;  // 0..255
    const int inner = i0 & 63;
    const int b     = (inner & 7) * 8 + (inner >> 3);  // bijective over 0..63
    const int rb    = i0 >> 6;                         // 0..3

    const int tid  = threadIdx.x;  // 0..511
    const int lane = tid & 63;
    const int wave = tid >> 6;     // 0..7
    const int wr   = wave >> 1;    // 32-row band of the 128 block rows
    const int wc   = wave & 1;     // 32-col half of each 64-col tile
    const int g    = lane >> 4;    // k-group 0..3
    const int ln   = lane & 15;

    const float* gV = V + (size_t)b * (CC * DD) + (size_t)rb * 128 * DD;
    const char*  gT = reinterpret_cast<const char*>(Tn + (size_t)b * (CC * DD));  // 512 B rows

    // ---- A prologue: load 128 fp32 V rows, L2-normalize, write bf16 swizzled to lds ----
    {
        const int rrow  = tid >> 3;        // 8 threads/row, 64 rows/pass
        const int ecolB = (tid & 7) * 64;  // byte offset of this thread's 32 bf16 elems
#pragma unroll
        for (int p = 0; p < 2; ++p) {
            const int row = p * 64 + rrow;
            const float4* src =
                reinterpret_cast<const float4*>(gV + (size_t)row * DD) + (tid & 7) * 8;
            float4 x[8];
#pragma unroll
            for (int q = 0; q < 8; ++q) x[q] = src[q];
            float ss = 0.f;
#pragma unroll
            for (int q = 0; q < 8; ++q)
                ss += x[q].x * x[q].x + x[q].y * x[q].y + x[q].z * x[q].z + x[q].w * x[q].w;
            ss += __shfl_xor(ss, 1);
            ss += __shfl_xor(ss, 2);
            ss += __shfl_xor(ss, 4);  // 8 lanes own the row
            const float rinv = 1.0f / fmaxf(sqrtf(ss), 1e-12f);
            char* dstrow = lds + row * 512;
            const int sw = SWZ(row);
#pragma unroll
            for (int q2 = 0; q2 < 4; ++q2) {
                const float4 v0 = x[2 * q2], v1 = x[2 * q2 + 1];
                bf16x8 o;
                o[0] = f2bf(v0.x * rinv); o[1] = f2bf(v0.y * rinv);
                o[2] = f2bf(v0.z * rinv); o[3] = f2bf(v0.w * rinv);
                o[4] = f2bf(v1.x * rinv); o[5] = f2bf(v1.y * rinv);
                o[6] = f2bf(v1.z * rinv); o[7] = f2bf(v1.w * rinv);
                *reinterpret_cast<bf16x8*>(dstrow + ((ecolB + q2 * 16) ^ sw)) = o;
            }
        }
    }
    __syncthreads();

    // ---- cache this wave's A fragments: rows [wr*32, +32) -> a[2][8] = 64 VGPR ----
    bf16x8 a[2][8];
#pragma unroll
    for (int i = 0; i < 2; ++i) {
        const int row  = wr * 32 + i * 16 + ln;
        const char* rp = lds + row * 512;
        const int sw   = SWZ(row);
#pragma unroll
        for (int kk = 0; kk < 8; ++kk)
            a[i][kk] = *reinterpret_cast<const bf16x8*>(rp + ((kk * 64 + g * 16) ^ sw));
    }
    __syncthreads();  // implicit vmcnt(0): clean counter; lds free for tile buffers

    // ---- DMA stage: tile t = 64 Tn rows (32 KB) -> buf[t%4]; wave stages rows [wave*8,+8) ----
    auto stage = [&](int t) {
        const char* gtile = gT + (size_t)t * 32768;
        char* dst = lds + (t & 3) * 32768 + wave * 4096;
#pragma unroll
        for (int r2 = 0; r2 < 4; ++r2) {
            const int L   = r2 * 1024 + (lane << 4);
            const int lr  = L >> 9;  // 0..7 local row (within wave's 8)
            const int row = wave * 8 + lr;
            const int inrow = L & 511;
            __builtin_amdgcn_global_load_lds(
                (const u32*)(gtile + (size_t)row * 512 + (inrow ^ SWZ(row))),
                (u32*)(dst + r2 * 1024), 16, 0, 0);
        }
    };
    stage(0);
    stage(1);
    stage(2);  // 12 loads in flight per wave (depth 3)

    float rs[2][4];  // rowsum of exp(2S) over this wave's cols, per (i, r)
    float dg[2][4];  // diagonal 2*S term
#pragma unroll
    for (int i = 0; i < 2; ++i)
#pragma unroll
        for (int r = 0; r < 4; ++r) { rs[i][r] = 0.f; dg[i][r] = 0.f; }

    for (int t = 0; t < 8; ++t) {  // NOT unrolled (register pressure)
        // counted wait: my 4 tile-t loads landed (t+1,t+2's 8 stay in flight); then all waves'
        if (t < 6)       asm volatile("s_waitcnt vmcnt(8)" ::: "memory");
        else if (t == 6) asm volatile("s_waitcnt vmcnt(4)" ::: "memory");
        else             asm volatile("s_waitcnt vmcnt(0)" ::: "memory");
        __builtin_amdgcn_s_barrier();
        __builtin_amdgcn_sched_barrier(0);
        // stage t+3 into buf[(t+3)%4] = buf[(t-1)%4]; the barrier above proved every wave
        // finished consuming tile t-1 -> WAR-safe with ONE barrier per tile
        if (t < 5) stage(t + 3);

        // ---- consume tile t: 16 ds_read + 32 MFMA (acc 2x2 fragments = 32x32 output) ----
        const char* bufp = lds + (t & 3) * 32768;
        const int row0 = wc * 32 + ln;        // jc=0 B-row
        const int row1 = wc * 32 + 16 + ln;   // jc=1 B-row
        const char* rp0 = bufp + row0 * 512;
        const char* rp1 = bufp + row1 * 512;
        const int sw0 = SWZ(row0), sw1 = SWZ(row1);
        f32x4 acc[2][2];
#pragma unroll
        for (int i = 0; i < 2; ++i)
#pragma unroll
            for (int j = 0; j < 2; ++j) acc[i][j] = (f32x4){0.f, 0.f, 0.f, 0.f};
        __builtin_amdgcn_s_setprio(1);
#pragma unroll
        for (int kk = 0; kk < 8; ++kk) {
            const int ko = kk * 64 + g * 16;
            const bf16x8 b0 = *reinterpret_cast<const bf16x8*>(rp0 + (ko ^ sw0));
            const bf16x8 b1 = *reinterpret_cast<const bf16x8*>(rp1 + (ko ^ sw1));
            acc[0][0] = __builtin_amdgcn_mfma_f32_16x16x32_bf16(a[0][kk], b0, acc[0][0], 0, 0, 0);
            acc[1][0] = __builtin_amdgcn_mfma_f32_16x16x32_bf16(a[1][kk], b0, acc[1][0], 0, 0, 0);
            acc[0][1] = __builtin_amdgcn_mfma_f32_16x16x32_bf16(a[0][kk], b1, acc[0][1], 0, 0, 0);
            acc[1][1] = __builtin_amdgcn_mfma_f32_16x16x32_bf16(a[1][kk], b1, acc[1][1], 0, 0, 0);
        }
        __builtin_amdgcn_s_setprio(0);

        // ---- fused epilogue: exp(2*S) partial rowsum; diagonal gated to its 2 tiles ----
        if ((t >> 1) == rb) {
#pragma unroll
            for (int i = 0; i < 2; ++i) {
                const int grow = rb * 128 + wr * 32 + i * 16 + g * 4;  // + r
#pragma unroll
                for (int j = 0; j < 2; ++j) {
                    const int gcol = t * 64 + wc * 32 + j * 16 + ln;
#pragma unroll
                    for (int r = 0; r < 4; ++r) {
                        const float s2 = acc[i][j][r] * 2.0f;
                        rs[i][r] += __expf(s2);
                        if (gcol == grow + r) dg[i][r] += s2;
                    }
                }
            }
        } else {
#pragma unroll
            for (int i = 0; i < 2; ++i)
#pragma unroll
                for (int j = 0; j < 2; ++j)
#pragma unroll
                    for (int r = 0; r < 4; ++r) rs[i][r] += __expf(acc[i][j][r] * 2.0f);
        }
    }

    // ---- per-row completion: combine the two wc-halves' exp-sums BEFORE log ----
#pragma unroll
    for (int i = 0; i < 2; ++i)
#pragma unroll
        for (int r = 0; r < 4; ++r) {
            float v = rs[i][r];
            float d = dg[i][r];
#pragma unroll
            for (int m = 1; m < 16; m <<= 1) {  // reduce the 16 column-lanes
                v += __shfl_xor(v, m);
                d += __shfl_xor(d, m);
            }
            if (ln == 0) {
                const int rl = wr * 32 + i * 16 + g * 4 + r;  // local row 0..127
                vred[rl * 2 + wc] = v;
                dred[rl * 2 + wc] = d;
            }
        }
    __syncthreads();

    if (tid < 128) {
        const float vv = vred[tid * 2] + vred[tid * 2 + 1];
        const float dd = dred[tid * 2] + dred[tid * 2 + 1];
        float lsum = logf(vv) - dd;
#pragma unroll
        for (int m = 1; m < 64; m <<= 1) lsum += __shfl_xor(lsum, m);
        if (lane == 0) red2[wave] = lsum;  // waves 0,1
    }
    __syncthreads();
    if (tid == 0) partials[i0] = red2[0] + red2[1];
}

// ---------------- Pass 3: final deterministic reduce (256 partials) ----------------
__global__ __launch_bounds__(256) void final_reduce(const float* __restrict__ partials,
                                                    float* __restrict__ out) {
    const int t = threadIdx.x;
    float v = partials[t];
#pragma unroll
    for (int m = 1; m < 64; m <<= 1) v += __shfl_xor(v, m);
    __shared__ float red[4];
    if ((t & 63) == 0) red[t >> 6] = v;
    __syncthreads();
    if (t == 0) out[0] = (red[0] + red[1] + red[2] + red[3]) * (1.0f / 32768.0f);
}

extern "C" void kernel_launch(void* const* d_in, const int* in_sizes, int n_in,
                              void* d_out, int out_size, void* d_ws, size_t ws_size,
                              hipStream_t stream) {
    const float* vis = (const float*)d_in[0];
    const float* txt = (const float*)d_in[1];

    unsigned short* Tn = (unsigned short*)d_ws;                             // 16.8 MB
    float* partials    = (float*)((char*)d_ws + (size_t)BB * CC * DD * 2);  // 256 floats
    float* out         = (float*)d_out;

    const int lds_bytes = 131072 + 256 * 4 + 256 * 4 + 16;
    hipFuncSetAttribute((const void*)gemm_loss, hipFuncAttributeMaxDynamicSharedMemorySize,
                        lds_bytes);

    norm_rows<<<8192, 256, 0, stream>>>(txt, Tn);
    gemm_loss<<<256, 512, lds_bytes, stream>>>(vis, Tn, partials);
    final_reduce<<<1, 256, 0, stream>>>(partials, out);
}